// Round 1
// baseline (11336.086 us; speedup 1.0000x reference)
//
#include <hip/hip_runtime.h>
#include <math.h>

#define HDIM 1024
#define BDIM 256
#define TSTEPS 64
#define TH3 3072

// Generic fp32 GEMM: C[M=256, ncols] = act(A[256,1024] @ W[1024, ncols] + bias)
// A row-major lda=1024. W row-major with row stride ldw (pointer pre-offset to col 0
// of this launch's slice). 64x64 tile per block, 256 threads, 4x4 microtile.
// act: 0 = none, 1 = relu, 2 = tanh. Optional second store C2 (ldc2) for d_out.
__global__ __launch_bounds__(256) void gemm64(
    const float* __restrict__ A,
    const float* __restrict__ W,
    const float* __restrict__ bias,
    float* __restrict__ C, int ldc,
    float* __restrict__ C2, int ldc2,
    int ldw, int act)
{
    __shared__ __align__(16) float As[16][64];   // As[k][row]
    __shared__ __align__(16) float Ws[16][64];   // Ws[k][col]

    const int tx = threadIdx.x;          // 0..15
    const int ty = threadIdx.y;          // 0..15
    const int tid = ty * 16 + tx;
    const int c0 = blockIdx.x * 64;
    const int r0 = blockIdx.y * 64;

    const int arow = tid >> 2;           // 0..63
    const int akk  = (tid & 3) << 2;     // 0,4,8,12
    const int wrow = tid >> 4;           // 0..15
    const int wcol = (tid & 15) << 2;    // 0..60

    float acc[4][4] = {};

    for (int k0 = 0; k0 < 1024; k0 += 16) {
        const float4 av = *(const float4*)(A + (size_t)(r0 + arow) * 1024 + k0 + akk);
        const float4 wv = *(const float4*)(W + (size_t)(k0 + wrow) * ldw + c0 + wcol);
        __syncthreads();
        As[akk + 0][arow] = av.x;
        As[akk + 1][arow] = av.y;
        As[akk + 2][arow] = av.z;
        As[akk + 3][arow] = av.w;
        *(float4*)&Ws[wrow][wcol] = wv;
        __syncthreads();
#pragma unroll
        for (int kk = 0; kk < 16; ++kk) {
            const float4 a4 = *(const float4*)&As[kk][ty << 2];
            const float4 w4 = *(const float4*)&Ws[kk][tx << 2];
            const float a[4] = {a4.x, a4.y, a4.z, a4.w};
            const float w[4] = {w4.x, w4.y, w4.z, w4.w};
#pragma unroll
            for (int i = 0; i < 4; ++i)
#pragma unroll
                for (int j = 0; j < 4; ++j)
                    acc[i][j] = fmaf(a[i], w[j], acc[i][j]);
        }
    }

    const float4 bv = *(const float4*)(bias + c0 + (tx << 2));
    const float bb[4] = {bv.x, bv.y, bv.z, bv.w};

#pragma unroll
    for (int i = 0; i < 4; ++i) {
        const int row = r0 + (ty << 2) + i;
        float v[4];
#pragma unroll
        for (int j = 0; j < 4; ++j) {
            float t = acc[i][j] + bb[j];
            if (act == 1) t = fmaxf(t, 0.0f);
            else if (act == 2) t = tanhf(t);
            v[j] = t;
        }
        float4 o = make_float4(v[0], v[1], v[2], v[3]);
        *(float4*)(C + (size_t)row * ldc + c0 + (tx << 2)) = o;
        if (C2) {
            *(float4*)(C2 + (size_t)row * ldc2 + c0 + (tx << 2)) = o;
        }
    }
}

// GRU gate math (Keras reset_after): h = z*h + (1-z)*tanh(xh + r*hh)
__global__ __launch_bounds__(256) void gru_gates(
    float* __restrict__ h,
    const float* __restrict__ mx,
    const float* __restrict__ mh)
{
    const int idx = blockIdx.x * 256 + threadIdx.x;  // 0 .. 256*1024-1
    const int b = idx >> 10;
    const int j = idx & 1023;
    const float* mxb = mx + (size_t)b * TH3;
    const float* mhb = mh + (size_t)b * TH3;
    const float xz = mxb[j],            hz = mhb[j];
    const float xr = mxb[HDIM + j],     hr = mhb[HDIM + j];
    const float xh = mxb[2 * HDIM + j], hh = mhb[2 * HDIM + j];
    const float z = 1.0f / (1.0f + __expf(-(xz + hz)));
    const float r = 1.0f / (1.0f + __expf(-(xr + hr)));
    const float cand = tanhf(xh + r * hh);
    const float hv = h[idx];
    h[idx] = z * hv + (1.0f - z) * cand;
}

extern "C" void kernel_launch(void* const* d_in, const int* in_sizes, int n_in,
                              void* d_out, int out_size, void* d_ws, size_t ws_size,
                              hipStream_t stream) {
    const float* x     = (const float*)d_in[0];
    const float* W_fs  = (const float*)d_in[1];
    const float* b_fs  = (const float*)d_in[2];
    const float* W_out = (const float*)d_in[3];
    const float* b_out = (const float*)d_in[4];
    const float* W_k   = (const float*)d_in[5];
    const float* W_r   = (const float*)d_in[6];
    const float* b_gru = (const float*)d_in[7];
    float* out = (float*)d_out;   // [B, T, H]

    float* h    = (float*)d_ws;            // [256,1024]
    float* outb = h    + BDIM * HDIM;      // [256,1024]
    float* mh   = outb + BDIM * HDIM;      // [256,3072]
    float* mx   = mh   + BDIM * TH3;       // [256,3072]

    dim3 blk(16, 16);
    dim3 gridH(16, 4);    // N=1024
    dim3 grid3(48, 4);    // N=3072

    // h0 = tanh(x @ W_fs + b_fs)
    gemm64<<<gridH, blk, 0, stream>>>(x, W_fs, b_fs, h, HDIM, nullptr, 0, HDIM, 2);

    for (int t = 0; t <= TSTEPS; ++t) {
        // out_t = relu(h_t @ W_out + b_out); store to d_out[:, t-1, :] for t>=1
        float* c2 = (t >= 1) ? (out + (size_t)(t - 1) * HDIM) : nullptr;
        gemm64<<<gridH, blk, 0, stream>>>(h, W_out, b_out, outb, HDIM,
                                          c2, TSTEPS * HDIM, HDIM, 1);
        if (t == TSTEPS) break;
        // mh = h @ W_r + b_gru[1]
        gemm64<<<grid3, blk, 0, stream>>>(h, W_r, b_gru + TH3, mh, TH3,
                                          nullptr, 0, TH3, 0);
        // mx = out @ W_k + b_gru[0]
        gemm64<<<grid3, blk, 0, stream>>>(outb, W_k, b_gru, mx, TH3,
                                          nullptr, 0, TH3, 0);
        // h = gates(h, mx, mh)
        gru_gates<<<dim3(BDIM * HDIM / 256), dim3(256), 0, stream>>>(h, mx, mh);
    }
}

// Round 2
// 7442.471 us; speedup vs baseline: 1.5232x; 1.5232x over previous
//
#include <hip/hip_runtime.h>
#include <math.h>

#define HDIM 1024
#define BDIM 256
#define TSTEPS 64
#define TH3 3072

__device__ __forceinline__ float sigmoidf_(float x) {
    return 1.0f / (1.0f + __expf(-x));
}

// gemmA: A[256,1024] @ [W0 (N=1024) | W1 (N=3072)] fused.
// Region0 (blockIdx.x < 16): C0 = act0(A@W0 + b0), optional C2 mirror store
//   (d_out slice, row stride 64*1024).
// Region1 (blockIdx.x >= 16): C1 = A@W1 + b1 (ldw1=3072, ld C1=3072).
// Tile 32 rows x 64 cols, 128 threads, 4x4 microtile, k-step 32.
__global__ __launch_bounds__(128) void gemmA(
    const float* __restrict__ A,
    const float* __restrict__ W0, const float* __restrict__ b0, int act0,
    float* __restrict__ C0, float* __restrict__ C2,
    const float* __restrict__ W1, const float* __restrict__ b1,
    float* __restrict__ C1)
{
    __shared__ __align__(16) float As[32][36];
    __shared__ __align__(16) float Ws[32][68];

    const int tid = threadIdx.x;
    const int bx = blockIdx.x, by = blockIdx.y;
    const int r0 = by * 32;
    const bool reg0 = (bx < 16);
    const int c0 = reg0 ? bx * 64 : (bx - 16) * 64;
    const float* __restrict__ W = reg0 ? W0 : W1;
    const int ldw = reg0 ? 1024 : 3072;

    const int arow = tid >> 2;            // 0..31
    const int ak   = (tid & 3) << 2;      // 0,4,8,12
    const int wrow = tid >> 4;            // 0..7
    const int wcol = (tid & 15) << 2;     // 0..60
    const int ty = tid >> 4;              // 0..7 -> rows 4*ty..
    const int tx = tid & 15;              // cols 4*tx..

    float acc[4][4] = {};

    const float* Ap = A + (size_t)(r0 + arow) * 1024 + ak;
    const float* Wp = W + (size_t)wrow * ldw + c0 + wcol;

    for (int k0 = 0; k0 < 1024; k0 += 32) {
        const float4 a0 = *(const float4*)(Ap + k0);
        const float4 a1 = *(const float4*)(Ap + k0 + 16);
        const float4 w0 = *(const float4*)(Wp + (size_t)k0 * ldw);
        const float4 w1 = *(const float4*)(Wp + (size_t)(k0 + 8) * ldw);
        const float4 w2 = *(const float4*)(Wp + (size_t)(k0 + 16) * ldw);
        const float4 w3 = *(const float4*)(Wp + (size_t)(k0 + 24) * ldw);
        __syncthreads();
        As[ak + 0][arow] = a0.x; As[ak + 1][arow] = a0.y;
        As[ak + 2][arow] = a0.z; As[ak + 3][arow] = a0.w;
        As[ak + 16][arow] = a1.x; As[ak + 17][arow] = a1.y;
        As[ak + 18][arow] = a1.z; As[ak + 19][arow] = a1.w;
        *(float4*)&Ws[wrow][wcol]      = w0;
        *(float4*)&Ws[wrow + 8][wcol]  = w1;
        *(float4*)&Ws[wrow + 16][wcol] = w2;
        *(float4*)&Ws[wrow + 24][wcol] = w3;
        __syncthreads();
#pragma unroll
        for (int kk = 0; kk < 32; ++kk) {
            const float4 a4 = *(const float4*)&As[kk][ty << 2];
            const float4 w4 = *(const float4*)&Ws[kk][tx << 2];
            const float a[4] = {a4.x, a4.y, a4.z, a4.w};
            const float w[4] = {w4.x, w4.y, w4.z, w4.w};
#pragma unroll
            for (int i = 0; i < 4; ++i)
#pragma unroll
                for (int j = 0; j < 4; ++j)
                    acc[i][j] = fmaf(a[i], w[j], acc[i][j]);
        }
    }

    const float* bias = reg0 ? b0 : b1;
    const float4 bv = *(const float4*)(bias + c0 + (tx << 2));
    const float bb[4] = {bv.x, bv.y, bv.z, bv.w};

#pragma unroll
    for (int i = 0; i < 4; ++i) {
        const int row = r0 + (ty << 2) + i;
        float v[4];
#pragma unroll
        for (int j = 0; j < 4; ++j) {
            float t = acc[i][j] + bb[j];
            if (reg0) {
                if (act0 == 1) t = fmaxf(t, 0.0f);
                else t = tanhf(t);
            }
            v[j] = t;
        }
        const float4 o = make_float4(v[0], v[1], v[2], v[3]);
        if (reg0) {
            *(float4*)(C0 + (size_t)row * 1024 + c0 + (tx << 2)) = o;
            if (C2)
                *(float4*)(C2 + (size_t)row * (TSTEPS * HDIM) + c0 + (tx << 2)) = o;
        } else {
            *(float4*)(C1 + (size_t)row * TH3 + c0 + (tx << 2)) = o;
        }
    }
}

// gemmB: mx = out @ W_k (+b_gru[0]) for a 16-wide j-slice across ALL 3 gate
// chunks, then fused GRU gate epilogue:
//   z = sig(mxz + mh_z); r = sig(mxr + mh_r); cand = tanh(mxh + r*mh_h)
//   h[b,j] = z*h + (1-z)*cand   (in place; each element owned by one thread)
// Tile 32 rows x (16 j x 3 chunks), 128 threads, microtile 4 rows x 1 j x 3.
__global__ __launch_bounds__(128) void gemmB(
    const float* __restrict__ A,        // outb [256,1024]
    const float* __restrict__ Wk,       // [1024,3072]
    const float* __restrict__ bg,       // b_gru row 0 (3072)
    const float* __restrict__ mh,       // [256,3072]
    float* __restrict__ h)              // [256,1024] in/out
{
    __shared__ __align__(16) float As[32][36];
    __shared__ __align__(16) float Ws[3][32][20];

    const int tid = threadIdx.x;
    const int j0 = blockIdx.x * 16;     // 0..1008
    const int r0 = blockIdx.y * 32;

    const int arow = tid >> 2;          // 0..31
    const int ak   = (tid & 3) << 2;
    const int wr   = tid >> 2;          // 0..31
    const int wc   = (tid & 3) << 2;    // 0,4,8,12
    const int ty = tid >> 4;            // 0..7
    const int tx = tid & 15;            // j = j0 + tx

    float acc[3][4] = {};

    const float* Ap = A + (size_t)(r0 + arow) * 1024 + ak;
    const float* Wp = Wk + (size_t)wr * TH3 + j0 + wc;

    for (int k0 = 0; k0 < 1024; k0 += 32) {
        const float4 a0 = *(const float4*)(Ap + k0);
        const float4 a1 = *(const float4*)(Ap + k0 + 16);
        float4 wv[3];
#pragma unroll
        for (int c = 0; c < 3; ++c)
            wv[c] = *(const float4*)(Wp + (size_t)k0 * TH3 + c * 1024);
        __syncthreads();
        As[ak + 0][arow] = a0.x; As[ak + 1][arow] = a0.y;
        As[ak + 2][arow] = a0.z; As[ak + 3][arow] = a0.w;
        As[ak + 16][arow] = a1.x; As[ak + 17][arow] = a1.y;
        As[ak + 18][arow] = a1.z; As[ak + 19][arow] = a1.w;
#pragma unroll
        for (int c = 0; c < 3; ++c)
            *(float4*)&Ws[c][wr][wc] = wv[c];
        __syncthreads();
#pragma unroll
        for (int kk = 0; kk < 32; ++kk) {
            const float4 a4 = *(const float4*)&As[kk][ty << 2];
            const float a[4] = {a4.x, a4.y, a4.z, a4.w};
            const float wz = Ws[0][kk][tx];
            const float wr_ = Ws[1][kk][tx];
            const float wh = Ws[2][kk][tx];
#pragma unroll
            for (int i = 0; i < 4; ++i) {
                acc[0][i] = fmaf(a[i], wz, acc[0][i]);
                acc[1][i] = fmaf(a[i], wr_, acc[1][i]);
                acc[2][i] = fmaf(a[i], wh, acc[2][i]);
            }
        }
    }

    const int j = j0 + tx;
    const float bz = bg[j];
    const float br = bg[HDIM + j];
    const float bh = bg[2 * HDIM + j];

#pragma unroll
    for (int i = 0; i < 4; ++i) {
        const int row = r0 + (ty << 2) + i;
        const float* mhp = mh + (size_t)row * TH3;
        const float z  = sigmoidf_(acc[0][i] + bz + mhp[j]);
        const float rg = sigmoidf_(acc[1][i] + br + mhp[HDIM + j]);
        const float cand = tanhf(acc[2][i] + bh + rg * mhp[2 * HDIM + j]);
        const size_t hi = (size_t)row * HDIM + j;
        const float ho = h[hi];
        h[hi] = z * ho + (1.0f - z) * cand;
    }
}

extern "C" void kernel_launch(void* const* d_in, const int* in_sizes, int n_in,
                              void* d_out, int out_size, void* d_ws, size_t ws_size,
                              hipStream_t stream) {
    const float* x     = (const float*)d_in[0];
    const float* W_fs  = (const float*)d_in[1];
    const float* b_fs  = (const float*)d_in[2];
    const float* W_out = (const float*)d_in[3];
    const float* b_out = (const float*)d_in[4];
    const float* W_k   = (const float*)d_in[5];
    const float* W_r   = (const float*)d_in[6];
    const float* b_gru = (const float*)d_in[7];
    float* out = (float*)d_out;            // [B, T, H]

    float* h    = (float*)d_ws;            // [256,1024]
    float* outb = h    + BDIM * HDIM;      // [256,1024]
    float* mh   = outb + BDIM * HDIM;      // [256,3072]

    const dim3 blk(128);
    const dim3 gridInit(16, 8);
    const dim3 gridA(64, 8);
    const dim3 gridB(64, 8);

    // h0 = tanh(x @ W_fs + b_fs)
    gemmA<<<gridInit, blk, 0, stream>>>(x, W_fs, b_fs, 2, h, nullptr,
                                        nullptr, nullptr, nullptr);

    for (int t = 0; t < TSTEPS; ++t) {
        float* c2 = (t >= 1) ? (out + (size_t)(t - 1) * HDIM) : nullptr;
        // [out | mh] = h @ [W_out | W_r]
        gemmA<<<gridA, blk, 0, stream>>>(h, W_out, b_out, 1, outb, c2,
                                         W_r, b_gru + TH3, mh);
        // mx = out @ W_k, fused gates -> h (in place)
        gemmB<<<gridB, blk, 0, stream>>>(outb, W_k, b_gru, mh, h);
    }
    // final out = relu(h @ W_out + b_out) -> d_out[:, 63, :]
    gemmA<<<gridInit, blk, 0, stream>>>(h, W_out, b_out, 1, outb,
                                        out + (size_t)(TSTEPS - 1) * HDIM,
                                        nullptr, nullptr, nullptr);
}